// Round 12
// baseline (159.190 us; speedup 1.0000x reference)
//
#include <hip/hip_runtime.h>

// LoRA linear, fp32 in/out: out = x @ (W + 2*B@A)^T + b
//   prep:   [0..511] Weff = bf16(W + 2*B@A) (2 MiB); [512..] xbf = bf16(x) (32 MiB).
//   gemm256: R12: 128x128x32, THREE-buffer pipeline, ONE barrier per tile.
//           R2/R7/R11 (2-barrier/phase structures) all plateau at 42.6-45.8us with
//           ~25us of barrier/waitcnt drain. 3 bufs make write-after-read distance
//           2 tiles -> per tile only {reads; stage j+2; vmcnt(2); lgkmcnt(0);
//           s_barrier; MFMA}: 33 barriers total (vs 64) and 48KB LDS -> 3 blocks/CU
//           (24 waves). Steady-state loop is branch-free (jj+=3, static buf roles).
//           Swizzle: R7-verified c^((r>>1)&3) on 64B rows (measured 0 conflicts).
//   Fallback (ws too small): old 128x128 kernel, A staged via fp32 loads + HW cvt.

typedef __bf16 bf16x8 __attribute__((ext_vector_type(8)));
typedef float f32x4 __attribute__((ext_vector_type(4)));
typedef unsigned short ushort8 __attribute__((ext_vector_type(8)));

__device__ __forceinline__ unsigned short f2bf(float f) {
    __bf16 h = (__bf16)f;                       // HW RNE convert
    union { __bf16 b; unsigned short u; } v; v.b = h; return v.u;
}
__device__ __forceinline__ ushort8 cvt8u(f32x4 a, f32x4 b) {
    ushort8 o;
#pragma unroll
    for (int i = 0; i < 4; ++i) { o[i] = f2bf(a[i]); o[i + 4] = f2bf(b[i]); }
    return o;
}
__device__ __forceinline__ void gld16(const void* g, void* l) {
    __builtin_amdgcn_global_load_lds(
        (const __attribute__((address_space(1))) unsigned int*)g,
        (__attribute__((address_space(3))) unsigned int*)l, 16, 0, 0);
}

#define FENCE() asm volatile("" ::: "memory")
#define BARRIER() do { FENCE(); __builtin_amdgcn_s_barrier(); FENCE(); } while (0)

// ---------------- prep: Weff fold + x conversion ----------------
__global__ __launch_bounds__(256) void prep(
    const float* __restrict__ X, const float* __restrict__ W,
    const float* __restrict__ A, const float* __restrict__ B,
    unsigned short* __restrict__ xbf, unsigned short* __restrict__ Weff)
{
    const int b = blockIdx.x;
    if (b < 512) {
        const int idx = b * 256 + threadIdx.x;
        const int o  = idx >> 7;
        const int kc = (idx & 127) << 3;
        float br[16];
#pragma unroll
        for (int r = 0; r < 16; ++r) br[r] = 2.0f * B[o * 16 + r];
        float acc[8];
        const float* wrow = W + (size_t)o * 1024 + kc;
#pragma unroll
        for (int j = 0; j < 8; ++j) acc[j] = wrow[j];
#pragma unroll
        for (int r = 0; r < 16; ++r) {
            const float* arow = A + r * 1024 + kc;
#pragma unroll
            for (int j = 0; j < 8; ++j) acc[j] += br[r] * arow[j];
        }
        ushort8 o8;
#pragma unroll
        for (int j = 0; j < 8; ++j) o8[j] = f2bf(acc[j]);
        *(ushort8*)(Weff + (size_t)o * 1024 + kc) = o8;
    } else {
        const size_t i = ((size_t)(b - 512) * 256 + threadIdx.x) * 8;
        f32x4 a = *(const f32x4*)(X + i);
        f32x4 c = *(const f32x4*)(X + i + 4);
        *(ushort8*)(xbf + i) = cvt8u(a, c);
    }
}

// ---------------- gemm256: 128x128x32, 3-buf, 1 barrier/tile, 3 blocks/CU --------
// Geometry: BM=BN=128, BK=32, 512 thr = 8 waves (4M x 2N: wr=w&3, wc=w>>2).
//   Per-wave out 32x64: m-frags rows (4*mt+wr)*16 (mt=0..1), n-frags cols
//   (2*nt+wc)*16 (nt=0..3). 8 MFMA + 6 ds_read_b128 + 2 gld16 per tile.
// LDS 48 KiB: 3 bufs (stride 16384 B) x {A bf16 [128][32] @0, B @8192}.
// Swizzle (64 B rows = 4 x 16B chunks): pos p of row r holds src chunk
//   p ^ ((r>>1)&3) — R7-verified reader (SQ_LDS_BANK_CONFLICT = 0), source
//   pre-swizzled, LDS dest linear (rule #21). Frag-row base (mult of 16) does
//   not perturb the hash: ((16k + r16)>>1)&3 == ((r16>>1)&3) + 8k-invariant.
// Per tile j (read buf R=j%3, stage j+2 -> buf S=(j+2)%3):
//   { ds_read fa[0..1], fb[0..3] from R;  gld16 A,B(j+2) -> S;
//     vmcnt(2) [retires A,B(j+1): queue = (j+1)x2 + (j+2)x2 = 4];
//     lgkmcnt(0) [own reads in regs BEFORE barrier -> no read-in-flight when a
//       later-tile stage lands in this buf];  s_barrier [all waves: j+1 landed,
//       all reads of S's previous contents done];  sched_barrier; 8 MFMA. }
// Writer-safety: S=(j+2)%3=(j-1)%3 was last read at tile j-1; those reads drained
//   at each wave's tile-(j-1) lgkmcnt BEFORE barrier j-1; stage issues after it.
// Peel: tiles 30 (vmcnt(0), no stage) and 31 (no waits beyond lgkmcnt).
__global__ __launch_bounds__(512, 6) void gemm256(
    const unsigned short* __restrict__ Xb,     // bf16 x [M][1024]
    const unsigned short* __restrict__ Wt,     // bf16 Weff [1024][1024]
    const float* __restrict__ bias,            // fp32 [1024]
    float* __restrict__ out)                   // fp32 [M][1024]
{
    extern __shared__ __align__(16) char lds[];   // 49152 B

    const int t    = threadIdx.x;
    const int lane = t & 63;
    const int w    = t >> 6;
    const int wr   = w & 3;         // 0..3 (M)
    const int wc   = w >> 2;        // 0..1 (N)
    const int r16  = lane & 15;
    const int quad = lane >> 4;

    // XCD-chunked block swizzle (nwg=1024 % 8 == 0 -> bijective).
    const int nwg = gridDim.x;
    int swz = blockIdx.x;
    if ((nwg & 7) == 0) swz = (swz & 7) * (nwg >> 3) + (swz >> 3);
    const int bm = (swz >> 3) * 128;           // 128 m-panels
    const int bn = (swz & 7) * 128;            // 8 n-panels share one x panel (L2)

    // ---- staging: thread t owns 16B chunk t of each 8 KB region ----
    // chunk t: row t>>2, pos t&3, src chunk (t&3)^((row>>1)&3)  [R7-verified]
    const int ar = t >> 2;                     // row 0..127
    const int ac = (t & 3) ^ ((ar >> 1) & 3);  // pre-swizzled src chunk
    const unsigned short* gA = Xb + (size_t)(bm + ar) * 1024 + ac * 8;
    const unsigned short* gB = Wt + (size_t)(bn + ar) * 1024 + ac * 8;
    const int adst = t * 16;                   // byte dest within region

    // ---- reader constants ----
    const int sw = (quad ^ ((r16 >> 1) & 3)) * 16;   // swizzled chunk (bytes)
    const int aB = wr * 1024 + r16 * 64 + sw;        // fa[mt] at aB + mt*4096
    const int bB = 8192 + wc * 1024 + r16 * 64 + sw; // fb[nt] at bB + nt*2048

    f32x4 acc[2][4];
#pragma unroll
    for (int i = 0; i < 2; ++i)
#pragma unroll
        for (int jj = 0; jj < 4; ++jj)
            acc[i][jj] = (f32x4){0.f, 0.f, 0.f, 0.f};

#define STAGE(BUF, K)                                                           \
    do { gld16(gA + (K), lds + (BUF) + adst);        FENCE();                   \
         gld16(gB + (K), lds + (BUF) + 8192 + adst); FENCE(); } while (0)

    // TILE: RB = read-buf byte base; SB = stage-buf byte base; STG in {0,1};
    // VM: 2 -> vmcnt(2), 0 -> vmcnt(0), -1 -> none. All args literal-foldable.
#define TILE(J, RB, SB, STG, VM)                                                \
    do {                                                                        \
        const char* Lb = lds + (RB);                                            \
        bf16x8 fa[2], fb[4];                                                    \
        fa[0] = *(const bf16x8*)(Lb + aB);                                      \
        fa[1] = *(const bf16x8*)(Lb + aB + 4096);                               \
        _Pragma("unroll")                                                       \
        for (int nt = 0; nt < 4; ++nt)                                          \
            fb[nt] = *(const bf16x8*)(Lb + bB + nt * 2048);                     \
        if (STG) STAGE((SB), ((J) + 2) * 32);                                   \
        if ((VM) == 2)      asm volatile("s_waitcnt vmcnt(2)" ::: "memory");    \
        else if ((VM) == 0) asm volatile("s_waitcnt vmcnt(0)" ::: "memory");    \
        asm volatile("s_waitcnt lgkmcnt(0)" ::: "memory");                      \
        BARRIER();                                                              \
        __builtin_amdgcn_sched_barrier(0); /* rule 18 */                        \
        __builtin_amdgcn_s_setprio(1);                                          \
        _Pragma("unroll")                                                       \
        for (int mt = 0; mt < 2; ++mt)                                          \
            _Pragma("unroll")                                                   \
            for (int nt = 0; nt < 4; ++nt)                                      \
                acc[mt][nt] = __builtin_amdgcn_mfma_f32_16x16x32_bf16(          \
                    fa[mt], fb[nt], acc[mt][nt], 0, 0, 0);                      \
        __builtin_amdgcn_s_setprio(0);                                          \
    } while (0)

    // ---- prologue: tile0 -> buf0, tile1 -> buf1 ----
    STAGE(0, 0);
    STAGE(16384, 32);
    asm volatile("s_waitcnt vmcnt(2)" ::: "memory");   // tile0 landed
    BARRIER();

    // ---- main loop: tiles 0..29, branch-free (static buffer roles) ----
    for (int jj = 0; jj < 30; jj += 3) {
        TILE(jj + 0, 0,     32768, 1, 2);   // read buf0, stage -> buf2
        TILE(jj + 1, 16384, 0,     1, 2);   // read buf1, stage -> buf0
        TILE(jj + 2, 32768, 16384, 1, 2);   // read buf2, stage -> buf1
    }
    // ---- peel: tiles 30 (buf0) and 31 (buf1) ----
    TILE(30, 0,     0, 0, 0);
    TILE(31, 16384, 0, 0, -1);

#undef TILE
#undef STAGE

    // ---- epilogue: frag (mt,nt) -> rows bm+(4mt+wr)*16+quad*4, cols bn+(2nt+wc)*16+r16 ----
    const int orow0 = bm + wr * 16 + quad * 4;
    const int ocol0 = bn + wc * 16 + r16;
#pragma unroll
    for (int nt = 0; nt < 4; ++nt) {
        const float bv = bias[ocol0 + nt * 32];
#pragma unroll
        for (int mt = 0; mt < 2; ++mt) {
            float* orow = out + (size_t)(orow0 + mt * 64) * 1024 + (ocol0 + nt * 32);
#pragma unroll
            for (int i = 0; i < 4; ++i)
                orow[(size_t)i * 1024] = acc[mt][nt][i] + bv;
        }
    }
}

// ---------------- fallback gemm (ws too small): old 128x128, fp32 A ----------------
template <bool XF32>
__global__ __launch_bounds__(256) void gemm_bt(
    const void* __restrict__ X_, const unsigned short* __restrict__ Wt,
    const float* __restrict__ bias, float* __restrict__ out)
{
    __shared__ __align__(16) unsigned short lA[128 * 32];
    __shared__ __align__(16) unsigned short lB[128 * 32];

    const int t    = threadIdx.x;
    const int lane = t & 63;
    const int w    = t >> 6;
    const int bm   = blockIdx.x * 128;
    const int bn   = blockIdx.y * 128;
    const int wm   = (w & 1) * 64;
    const int wn   = (w >> 1) * 64;
    const int r16  = lane & 15;
    const int quad = lane >> 4;

    const int srow = t >> 2;
    const int gc   = (t & 3) ^ ((srow >> 1) & 3);
    unsigned short* lsA = lA + t * 8;
    unsigned short* lsB = lB + t * 8;
    const size_t ga0 = (size_t)(bm + srow) * 1024 + gc * 8;
    const size_t ga1 = (size_t)(bm + srow + 64) * 1024 + gc * 8;
    const unsigned short* gB0 = Wt + (size_t)(bn + srow) * 1024 + gc * 8;

    const int p    = (quad ^ ((r16 >> 1) & 3)) * 8;
    const int aoff = (wm + r16) * 32 + p;
    const int boff = (wn + r16) * 32 + p;

    const unsigned short* Xb = (const unsigned short*)X_;
    const float*          Xf = (const float*)X_;

    f32x4 acc[4][4];
#pragma unroll
    for (int i = 0; i < 4; ++i)
#pragma unroll
        for (int j = 0; j < 4; ++j) {
            f32x4 z = {0.f, 0.f, 0.f, 0.f};
            acc[i][j] = z;
        }

    for (int kt = 0; kt < 1024; kt += 32) {
        if (XF32) {
            f32x4 a0 = *(const f32x4*)(Xf + ga0 + kt);
            f32x4 a1 = *(const f32x4*)(Xf + ga0 + kt + 4);
            f32x4 a2 = *(const f32x4*)(Xf + ga1 + kt);
            f32x4 a3 = *(const f32x4*)(Xf + ga1 + kt + 4);
            *(ushort8*)lsA          = cvt8u(a0, a1);
            *(ushort8*)(lsA + 2048) = cvt8u(a2, a3);
        } else {
            gld16(Xb + ga0 + kt, lsA);
            gld16(Xb + ga1 + kt, lsA + 2048);
        }
        gld16(gB0 + kt,             lsB);
        gld16(gB0 + kt + 64 * 1024, lsB + 2048);
        __syncthreads();

        bf16x8 fa[4], fb[4];
#pragma unroll
        for (int mt = 0; mt < 4; ++mt) fa[mt] = *(const bf16x8*)(lA + aoff + mt * 16 * 32);
#pragma unroll
        for (int nt = 0; nt < 4; ++nt) fb[nt] = *(const bf16x8*)(lB + boff + nt * 16 * 32);

#pragma unroll
        for (int mt = 0; mt < 4; ++mt)
#pragma unroll
            for (int nt = 0; nt < 4; ++nt)
                acc[mt][nt] = __builtin_amdgcn_mfma_f32_16x16x32_bf16(
                    fa[mt], fb[nt], acc[mt][nt], 0, 0, 0);

        __syncthreads();
    }

    const int orow0 = bm + wm + quad * 4;
    const int ocol0 = bn + wn + r16;
#pragma unroll
    for (int nt = 0; nt < 4; ++nt) {
        const float bv = bias[ocol0 + nt * 16];
#pragma unroll
        for (int mt = 0; mt < 4; ++mt)
#pragma unroll
            for (int i = 0; i < 4; ++i)
                out[(size_t)(orow0 + mt * 16 + i) * 1024 + (ocol0 + nt * 16)] =
                    acc[mt][nt][i] + bv;
    }
}

extern "C" void kernel_launch(void* const* d_in, const int* in_sizes, int n_in,
                              void* d_out, int out_size, void* d_ws, size_t ws_size,
                              hipStream_t stream) {
    const float* x  = (const float*)d_in[0];   // [M][1024]
    const float* W  = (const float*)d_in[1];   // [1024][1024]
    const float* b  = (const float*)d_in[2];   // [1024]
    const float* A  = (const float*)d_in[3];   // [16][1024]
    const float* Bm = (const float*)d_in[4];   // [1024][16]
    float* out = (float*)d_out;

    const int M = in_sizes[0] / 1024;          // 16384

    const bool fast = (ws_size >= ((size_t)(M)*1024*2 + (2u << 20) + 4096)) &&
                      (M % 128 == 0);
    if (fast) {
        unsigned short* xbf  = (unsigned short*)d_ws;
        unsigned short* Weff = xbf + (size_t)M * 1024;
        hipLaunchKernelGGL(prep, dim3(512 + M / 2), dim3(256), 0, stream,
                           x, W, A, Bm, xbf, Weff);
        hipLaunchKernelGGL(gemm256, dim3((M / 128) * 8), dim3(512), 49152, stream,
                           xbf, Weff, b, out);
    } else {
        unsigned short* Weff = (unsigned short*)d_ws;
        hipLaunchKernelGGL(prep, dim3(512), dim3(256), 0, stream,
                           x, W, A, Bm, (unsigned short*)nullptr, Weff);
        hipLaunchKernelGGL((gemm_bt<true>), dim3(M / 128, 8), dim3(256), 0, stream,
                           (const void*)x, Weff, b, out);
    }
}